// Round 5
// baseline (318.265 us; speedup 1.0000x reference)
//
#include <hip/hip_runtime.h>

// PseudoImageScatter: img[f, y, x] = pillar_features[p, f], last pillar wins.
// Pass 1: winner[y*W+x] = atomicMax(pillar idx)  (last-wins == max idx)
// Pass 2: 256-cell tiles, feature-major LDS transpose, two f-halves of 32.
//   Phase A: 8 lanes per half-row -> one wave-instr gathers 8 contiguous,
//            128B-aligned half-rows (8 cache lines, not 64). LDS writes are
//            XOR-swizzled (col ^ ((f>>2)&3)<<3) -> 2-way banks (free).
//   Phase B: 16B-aligned swizzled LDS reads + 1 KiB contiguous nontemporal
//            store per plane per wave instruction (write-once 268 MB stream).

constexpr int H    = 1024;
constexpr int W    = 1024;
constexpr int HW   = H * W;
constexpr int NF   = 64;
constexpr int TILE = 256;           // cells per block
constexpr int HALF = 32;            // features per LDS pass

typedef float nt4 __attribute__((ext_vector_type(4)));  // native vec for nontemporal

__global__ void winner_kernel(const int* __restrict__ coords,
                              int* __restrict__ winner, int np) {
    int p = blockIdx.x * blockDim.x + threadIdx.x;
    if (p >= np) return;
    int y = coords[p * 3 + 1];
    int x = coords[p * 3 + 2];
    if ((unsigned)x < (unsigned)W && (unsigned)y < (unsigned)H) {
        atomicMax(winner + (y * W + x), p);   // device-scope, cross-XCD safe
    }
}

__global__ void __launch_bounds__(256) fill_kernel(const float* __restrict__ feat,
                                                   const int* __restrict__ winner,
                                                   float* __restrict__ out) {
    __shared__ float lds[HALF * TILE];        // 32 KiB, f-major, XOR-swizzled cols
    __shared__ int   wc[TILE];

    const int base = blockIdx.x * TILE;
    const int t    = threadIdx.x;
    const int wv   = t >> 6;                  // wave 0..3
    const int l    = t & 63;                  // lane
    const int q    = t & 7;                   // float4 slot within half-row, 0..7
    const int g    = t >> 3;                  // cell-slot 0..31 per round
    const int xorX = (q & 3) << 3;            // phase-A column swizzle

    wc[t] = winner[base + t];                 // coalesced, all 256 threads
    __syncthreads();

    for (int h = 0; h < 2; ++h) {
        // ---- Phase A: 8 rounds x 32 cells; 8 lanes cooperate on one half-row.
#pragma unroll
        for (int r = 0; r < 8; ++r) {
            const int c   = r * 32 + g;
            const int wp  = wc[c];
            const int col = c ^ xorX;
            float* dst = lds + (q * 4) * TILE + col;     // rows 4q..4q+3 of this half
            if (wp >= 0) {
                float4 v = *(const float4*)(feat + (size_t)wp * NF + h * HALF + q * 4);
                dst[0 * TILE] = v.x;
                dst[1 * TILE] = v.y;
                dst[2 * TILE] = v.z;
                dst[3 * TILE] = v.w;
            } else {
                dst[0 * TILE] = 0.0f;
                dst[1 * TILE] = 0.0f;
                dst[2 * TILE] = 0.0f;
                dst[3 * TILE] = 0.0f;
            }
        }
        __syncthreads();

        // ---- Phase B: wave wv writes plane f = h*32 + p*4 + wv;
        // LDS read un-swizzles (X = (p&3)<<3, 16B-aligned), store is 1 KiB
        // contiguous per wave instruction.
#pragma unroll
        for (int p = 0; p < 8; ++p) {
            const int floc = p * 4 + wv;                 // floc>>2 == p
            const int X    = (p & 3) << 3;
            nt4 v = *(const nt4*)&lds[floc * TILE + ((l * 4) ^ X)];
            __builtin_nontemporal_store(
                v, (nt4*)(out + (size_t)(h * HALF + floc) * HW + base + l * 4));
        }
        __syncthreads();                      // before next half reuses LDS
    }
}

extern "C" void kernel_launch(void* const* d_in, const int* in_sizes, int n_in,
                              void* d_out, int out_size, void* d_ws, size_t ws_size,
                              hipStream_t stream) {
    const float* feat   = (const float*)d_in[0];
    const int*   coords = (const int*)d_in[1];
    float*       out    = (float*)d_out;
    int np = in_sizes[1] / 3;

    int* winner = (int*)d_ws;   // HW ints = 4 MiB scratch

    (void)hipMemsetAsync(winner, 0xFF, (size_t)HW * sizeof(int), stream);  // winner := -1
    winner_kernel<<<(np + 255) / 256, 256, 0, stream>>>(coords, winner, np);
    fill_kernel<<<HW / TILE, 256, 0, stream>>>(feat, winner, out);
}

// Round 6
// 300.843 us; speedup vs baseline: 1.0579x; 1.0579x over previous
//
#include <hip/hip_runtime.h>

// PseudoImageScatter: img[f, y, x] = pillar_features[p, f], last pillar wins.
// Pass 1: winner[y*W+x] = atomicMax(pillar idx)  (last-wins == max idx)
// Pass 2: 256-cell tiles, feature-major LDS transpose, two f-halves of 32.
//   LDS zeroed ONCE (vectorized, conflict-free); only occupied cells (~10%)
//   ever write it after that — phase A gather is exec-masked sparse (cheap).
//   Phase B: ds_read_b128 + 1 KiB contiguous nontemporal store per wave instr.

constexpr int H    = 1024;
constexpr int W    = 1024;
constexpr int HW   = H * W;
constexpr int NF   = 64;
constexpr int TILE = 256;           // cells per block
constexpr int HALF = 32;            // features per LDS pass

typedef float nt4 __attribute__((ext_vector_type(4)));  // native vec for nontemporal

__global__ void winner_kernel(const int* __restrict__ coords,
                              int* __restrict__ winner, int np) {
    int p = blockIdx.x * blockDim.x + threadIdx.x;
    if (p >= np) return;
    int y = coords[p * 3 + 1];
    int x = coords[p * 3 + 2];
    if ((unsigned)x < (unsigned)W && (unsigned)y < (unsigned)H) {
        atomicMax(winner + (y * W + x), p);   // device-scope, cross-XCD safe
    }
}

__global__ void __launch_bounds__(256, 4) fill_kernel(const float* __restrict__ feat,
                                                      const int* __restrict__ winner,
                                                      float* __restrict__ out) {
    __shared__ float lds[HALF * TILE];        // 32 KiB, f-major -> 4 blocks/CU

    const int base = blockIdx.x * TILE;
    const int t    = threadIdx.x;             // == cell within tile (phase A)
    const int wv   = t >> 6;                  // wave 0..3
    const int l    = t & 63;                  // lane

    const int wp = winner[base + t];          // coalesced

    // ---- Zero LDS once. lanes write lds[j*1024 + t*4]: bank = t*4 % 32,
    // contiguous across the wave -> conflict-free b128 pattern. Empty columns
    // are never touched again, so they stay zero for BOTH halves.
    {
        float4 z = {0.0f, 0.0f, 0.0f, 0.0f};
#pragma unroll
        for (int j = 0; j < 8; ++j)
            *(float4*)&lds[j * 1024 + t * 4] = z;
    }
    __syncthreads();

    const float4* row = (const float4*)(feat + (size_t)max(wp, 0) * NF);

    for (int h = 0; h < 2; ++h) {
        // ---- Phase A: occupied threads (~10%, exec-masked) stage 32 features
        // of their cell, f-major. bank = t%32 per instr -> 2-way = free.
        if (wp >= 0) {
#pragma unroll
            for (int j = 0; j < 8; ++j) {
                float4 r = row[h * 8 + j];
                lds[(j * 4 + 0) * TILE + t] = r.x;
                lds[(j * 4 + 1) * TILE + t] = r.y;
                lds[(j * 4 + 2) * TILE + t] = r.z;
                lds[(j * 4 + 3) * TILE + t] = r.w;
            }
        }
        __syncthreads();

        // ---- Phase B: wave wv writes plane f = h*32 + p*4 + wv, cells
        // base..base+255: 64 lanes x 16 B = 1 KiB contiguous per instr.
#pragma unroll
        for (int p = 0; p < 8; ++p) {
            const int floc = p * 4 + wv;
            nt4 v = *(const nt4*)&lds[floc * TILE + l * 4];
            __builtin_nontemporal_store(
                v, (nt4*)(out + (size_t)(h * HALF + floc) * HW + base + l * 4));
        }
        __syncthreads();   // B(h) must finish before A(h+1) overwrites columns
    }
}

extern "C" void kernel_launch(void* const* d_in, const int* in_sizes, int n_in,
                              void* d_out, int out_size, void* d_ws, size_t ws_size,
                              hipStream_t stream) {
    const float* feat   = (const float*)d_in[0];
    const int*   coords = (const int*)d_in[1];
    float*       out    = (float*)d_out;
    int np = in_sizes[1] / 3;

    int* winner = (int*)d_ws;   // HW ints = 4 MiB scratch

    (void)hipMemsetAsync(winner, 0xFF, (size_t)HW * sizeof(int), stream);  // winner := -1
    winner_kernel<<<(np + 255) / 256, 256, 0, stream>>>(coords, winner, np);
    fill_kernel<<<HW / TILE, 256, 0, stream>>>(feat, winner, out);
}